// Round 1
// baseline (860.168 us; speedup 1.0000x reference)
//
#include <hip/hip_runtime.h>

#define B_    32
#define C_    16
#define N_    64
#define T_    4096
#define OUT_  16
#define CNT_  (C_ * N_ * T_)   // x batch stride
#define ONT_  (OUT_ * N_ * T_) // y batch stride

typedef __attribute__((ext_vector_type(8))) short short8;   // 8 bf16 (4 VGPR) MFMA A/B frag
typedef __attribute__((ext_vector_type(4))) short short4v;  // 8-byte LDS load
typedef __attribute__((ext_vector_type(4))) float floatx4;  // MFMA C/D frag

__device__ __forceinline__ unsigned short f32_to_bf16(float f) {
    unsigned int x = __builtin_bit_cast(unsigned int, f);
    x = (x + 0x7FFFu + ((x >> 16) & 1u)) >> 16;   // round-nearest-even
    return (unsigned short)x;
}

// ---------------------------------------------------------------------------
// Kernel 1: W[oi][j] = sum_n U[i][n] * theta[n][o] * U[j][n]   (oi = o*64+i)
// Stored bf16, row-major, 64 per row (128 B rows). 1024x64 = 128 KiB.
// ---------------------------------------------------------------------------
__global__ __launch_bounds__(256)
void build_w(const float* __restrict__ U, const float* __restrict__ theta,
             unsigned short* __restrict__ W) {
    __shared__ float Ul[64 * 65];   // padded: bank-conflict-free column reads
    __shared__ float Th[64 * 16];

    const int tid = threadIdx.x;
    #pragma unroll
    for (int k = 0; k < 16; ++k) {
        int e = tid + k * 256;                       // 4096 elements
        Ul[(e >> 6) * 65 + (e & 63)] = U[e];
    }
    #pragma unroll
    for (int k = 0; k < 4; ++k) {
        int e = tid + k * 256;                       // 1024 elements
        Th[e] = theta[e];
    }
    __syncthreads();

    const int idx = blockIdx.x * 256 + tid;          // 0..65535
    const int j  = idx & 63;
    const int oi = idx >> 6;
    const int i  = oi & 63;
    const int o  = oi >> 6;

    float s = 0.f;
    #pragma unroll
    for (int n = 0; n < 64; ++n)
        s += Ul[i * 65 + n] * Th[n * 16 + o] * Ul[j * 65 + n];

    W[idx] = f32_to_bf16(s);
}

// ---------------------------------------------------------------------------
// Kernel 2 (fused): per (b, 128-wide t-tile):
//   phase 1: xsum[j][t] = sum_c x[b,c,j,t]  -> LDS bf16, [t][j] layout
//   phase 2: y[oi][t]   = sum_j W[oi][j] * xsum[j][t]  via 16x16x32 bf16 MFMA
// ---------------------------------------------------------------------------
__global__ __launch_bounds__(256, 2)
void spectral_fused(const float* __restrict__ x,
                    const unsigned short* __restrict__ W,
                    float* __restrict__ y) {
    // [t][j] bf16, rows padded 64->68 (136 B): 8B-aligned b64 frag reads, ~2-way banks
    __shared__ unsigned short xs[128][68];

    const int b   = blockIdx.y;
    const int t0  = blockIdx.x * 128;
    const int tid = threadIdx.x;

    // ---- Phase 1: channel reduction, coalesced float4 along t ----
    {
        const int tq = tid & 31;          // which float4 group in the 128-wide tile
        const int jh = tid >> 5;          // 0..7
        const float* xb = x + (size_t)b * CNT_ + t0 + tq * 4;
        #pragma unroll
        for (int it = 0; it < 8; ++it) {
            const int j = it * 8 + jh;
            const float4* p = (const float4*)(xb + (size_t)j * T_);
            float ax = 0.f, ay = 0.f, az = 0.f, aw = 0.f;
            #pragma unroll
            for (int c = 0; c < 16; ++c) {
                float4 v = p[(size_t)c * (N_ * T_ / 4)];
                ax += v.x; ay += v.y; az += v.z; aw += v.w;
            }
            const int tt = tq * 4;
            xs[tt + 0][j] = f32_to_bf16(ax);
            xs[tt + 1][j] = f32_to_bf16(ay);
            xs[tt + 2][j] = f32_to_bf16(az);
            xs[tt + 3][j] = f32_to_bf16(aw);
        }
    }
    __syncthreads();

    // ---- Phase 2: MFMA. Wave w owns oi rows [w*256, w*256+256) ----
    const int wave = tid >> 6;
    const int lane = tid & 63;
    const int q    = lane >> 4;     // quad 0..3
    const int c16  = lane & 15;

    // B fragments: B[k=j][n=t]; lane holds k = q*8+jj, n = c16.
    // 8 t-tiles x 2 k-steps, resident in registers (64 VGPR).
    short8 bfrag[8][2];
    #pragma unroll
    for (int tt = 0; tt < 8; ++tt) {
        #pragma unroll
        for (int ks = 0; ks < 2; ++ks) {
            const unsigned short* src = &xs[tt * 16 + c16][ks * 32 + q * 8];
            short4v lo = *(const short4v*)(src);
            short4v hi = *(const short4v*)(src + 4);
            bfrag[tt][ks] = short8{lo.x, lo.y, lo.z, lo.w, hi.x, hi.y, hi.z, hi.w};
        }
    }

    const short* Wp = (const short*)W;
    float* yb = y + (size_t)b * ONT_ + t0;

    #pragma unroll 1
    for (int ot = 0; ot < 16; ++ot) {
        const int oi_base = wave * 256 + ot * 16;
        // A fragments: A[m=oi][k=j]; lane holds row oi_base+c16, k = ks*32+q*8+jj.
        // W row-major 64/row -> 16B-aligned dwordx4 loads (L2-resident table).
        const short* arow = Wp + (size_t)(oi_base + c16) * 64 + q * 8;
        short8 a0 = *(const short8*)(arow);        // k = 0..31 slice
        short8 a1 = *(const short8*)(arow + 32);   // k = 32..63 slice
        #pragma unroll
        for (int tt = 0; tt < 8; ++tt) {
            floatx4 acc = {0.f, 0.f, 0.f, 0.f};
            acc = __builtin_amdgcn_mfma_f32_16x16x32_bf16(a0, bfrag[tt][0], acc, 0, 0, 0);
            acc = __builtin_amdgcn_mfma_f32_16x16x32_bf16(a1, bfrag[tt][1], acc, 0, 0, 0);
            // D: row = q*4+r, col = c16
            float* ybase = yb + tt * 16 + c16;
            #pragma unroll
            for (int r = 0; r < 4; ++r)
                ybase[(size_t)(oi_base + q * 4 + r) * T_] = acc[r];
        }
    }
}

extern "C" void kernel_launch(void* const* d_in, const int* in_sizes, int n_in,
                              void* d_out, int out_size, void* d_ws, size_t ws_size,
                              hipStream_t stream) {
    (void)in_sizes; (void)n_in; (void)out_size; (void)ws_size;
    const float* x     = (const float*)d_in[0];
    const float* U     = (const float*)d_in[1];
    const float* theta = (const float*)d_in[2];
    float* y           = (float*)d_out;
    unsigned short* W  = (unsigned short*)d_ws;   // 1024*64*2 = 128 KiB scratch

    build_w<<<dim3(256), dim3(256), 0, stream>>>(U, theta, W);
    spectral_fused<<<dim3(T_ / 128, B_), dim3(256), 0, stream>>>(x, W, y);
}